// Round 9
// baseline (288.686 us; speedup 1.0000x reference)
//
#include <hip/hip_runtime.h>
#include <hip/hip_bf16.h>
#include <cstdint>

typedef __attribute__((ext_vector_type(16))) float  floatx16;
typedef __attribute__((ext_vector_type(8)))  __bf16 bf16x8;

#define M_T 8192   // tokens
#define N_T 4096   // out features
#define K_T 4096   // in features
#define NG  32

// fp32 -> bf16 round-to-nearest-even
__device__ __forceinline__ unsigned short f2bf(float f) {
    union { float f; unsigned int u; } v; v.f = f;
    unsigned int u = v.u;
    u += 0x7fffu + ((u >> 16) & 1u);
    return (unsigned short)(u >> 16);
}

// async global->LDS, 16B per lane; LDS dest wave-uniform base + lane*16.
__device__ __forceinline__ void load_lds16(const void* gsrc, void* ldst) {
    __builtin_amdgcn_global_load_lds(
        (const __attribute__((address_space(1))) uint32_t*)gsrc,
        (__attribute__((address_space(3))) uint32_t*)ldst,
        16, 0, 0);
}

// ---------------- merged prep kernel (verified) ----------------
__global__ void prep_kernel(const int* __restrict__ q,
                            const float* __restrict__ sc,
                            const float* __restrict__ zr,
                            const float* __restrict__ X,
                            unsigned short* __restrict__ Wb,
                            unsigned short* __restrict__ Xb) {
    int b = blockIdx.x;
    if (b < 16384) {
        int idx = b * 256 + threadIdx.x;
        int e0 = idx << 2;
        int row = e0 >> 12;
        int col = e0 & 4095;
        int g = col >> 7;
        float s = sc[(row << 5) + g];
        float z = zr[(row << 5) + g];
        int4 qv = *(const int4*)(q + e0);
        ushort4 o;
        o.x = f2bf(((float)qv.x - z) * s);
        o.y = f2bf(((float)qv.y - z) * s);
        o.z = f2bf(((float)qv.z - z) * s);
        o.w = f2bf(((float)qv.w - z) * s);
        *(ushort4*)(Wb + e0) = o;
    } else {
        int idx = (b - 16384) * 256 + threadIdx.x;
        int e0 = idx << 2;
        float4 xv = *(const float4*)(X + e0);
        ushort4 o;
        o.x = f2bf(xv.x); o.y = f2bf(xv.y); o.z = f2bf(xv.z); o.w = f2bf(xv.w);
        *(ushort4*)(Xb + e0) = o;
    }
}

// ------- 256x256 8-phase GEMM, 32x32x16 MFMA, read-ahead, 6 barriers/8 ------
// C[M][N] = Xb[M][K] * Wb[N][K]^T + bias.   (R8 structure; phase = k-step)
// 8 waves (2M x 4N), BK=64, LDS 128 KiB = 2 bufs x (A 2 halves + B 2 halves).
// Phases 0-3 compute buf0 (tile 2t) ksteps 0-3; 4-7 buf1 (tile 2t+1).
// Per phase: 8x mfma_f32_32x32x16_bf16 (mf 0..3 x nf 0..1), inputs preloaded
// at the PREVIOUS phase's tail:
//   q0-tail: bfr[2][.],bfr[3][.]<-B k2,k3 (4) + a<-A k1 (4)
//   q1-tail: a<-A k2 (4)          q2-tail: a<-A k3 (4)
//   q3-tail: bfr[0][.],bfr[1][.]<-B' k0,k1 + a<-A' k0   (other buffer)
// => B's last ds_read of a buffer is at its q0-tail (regs hold k2,k3 copies),
//    A's last ds_read at q2-tail -> same hazard windows as R8; ledger carries.
// Stage: ph0:buf1.A0<-t1 ph1:buf1.A1<-t1 ph2:buf0.B0<-t2 ph3:buf0.B1<-t2
//        ph4:buf0.A0<-t2 ph5:buf0.A1<-t2 ph6:buf1.B0<-t3 ph7:buf1.B1<-t3
// Waits: q1-end lgkmcnt(4) (drains q0-tail B/A reads, keeps q1's 4 A-reads in
// flight) before ph2/ph6 B-staging; q2-end vmcnt(2) publishes the other
// buffer (drains all but this phase's 2 stage loads; counted, never 0), the
// q2-end barrier makes it WG-wide; q3-end barrier separates A-MFMA drain from
// restaging. Barriers at q==1,2,3 only (ph0/ph4-end removed, R8 proof).
// Fragment maps (32x32x16 bf16): A/B lane l holds 8 contiguous K at
// row=l&31, kgrp=l>>5. C/D: col=lane&31, row=(r&3)+8*(r>>2)+4*(lane>>5).
__global__ __launch_bounds__(512, 2) void gemm256_32x32(
    const unsigned short* __restrict__ Xb,
    const unsigned short* __restrict__ Wb,
    const float* __restrict__ bias,
    float* __restrict__ C)
{
    __shared__ __align__(16) unsigned short lds[65536];   // 128 KiB
    char* ldsb = (char*)lds;

    const int tid  = threadIdx.x;
    const int lane = tid & 63;
    const int wid  = tid >> 6;
    const int wm   = wid >> 2;    // 0..1
    const int wn   = wid & 3;     // 0..3

    // 2D XCD-aware swizzle. grid=512 = 8 XCD regions of 8Mx8N tiles.
    int bid = blockIdx.x;
    int xcd = bid & 7, r0 = bid >> 3;
    int mt = (xcd >> 1) * 8 + (r0 & 7);
    int nt = (xcd & 1) * 8 + (r0 >> 3);
    const int bm = mt * 256;
    const int bn = nt * 256;

    floatx16 acc[4][2] = {};

    const int l31  = lane & 31;
    const int ksub = (lane >> 5) * 16;        // k-group byte offset
    const int xorv = (lane & 7) << 4;         // swizzle (row&7 == lane&7)

    // precomputed LDS byte offsets per (buf, kstep); mf*4096 / nf*4096 folded
    // into ds_read immediates at call sites (compile-time).
    int obA[2][4], obB[2][4];
    #pragma unroll
    for (int b = 0; b < 2; ++b)
        #pragma unroll
        for (int k = 0; k < 4; ++k) {
            obA[b][k] = b * 65536 + wm * 16384 + l31 * 128
                      + ((k * 32 + ksub) ^ xorv);
            obB[b][k] = b * 65536 + 32768 + (wn >> 1) * 16384 + (wn & 1) * 8192
                      + l31 * 128 + ((k * 32 + ksub) ^ xorv);
        }

    auto rA = [&](int b, int k, int mf) -> bf16x8 {
        return *(const bf16x8*)(ldsb + obA[b][k] + mf * 4096);
    };
    auto rB = [&](int b, int k, int nf) -> bf16x8 {
        return *(const bf16x8*)(ldsb + obB[b][k] + nf * 4096);
    };

    const int pl0 = (wid * 8 + (lane >> 3)) * 8192
                  + (((lane & 7) * 16) ^ ((lane >> 3) << 4));
    const int pl1 = pl0 + 64 * 8192;
    const char* GA = (const char*)Xb + (size_t)bm * 8192;
    const char* GB = (const char*)Wb + (size_t)bn * 8192;

    auto stage_half = [&](int buf, int isB, int half, int tk, const char* G) {
        char* dst = ldsb + buf * 65536 + isB * 32768 + half * 16384 + wid * 1024;
        const char* s0 = G + ((size_t)half * 1048576 + (size_t)tk * 128);
        load_lds16(s0 + pl0, dst);
        load_lds16(s0 + pl1, dst + 8192);
    };

    // ---- prologue: buf0 <- tile0 (B,B,A,A), buf1.B <- tile1 ----
    stage_half(0, 1, 0, 0, GB);
    stage_half(0, 1, 1, 0, GB);
    stage_half(0, 0, 0, 0, GA);
    stage_half(0, 0, 1, 0, GA);
    stage_half(1, 1, 0, 1, GB);
    stage_half(1, 1, 1, 1, GB);
    asm volatile("s_waitcnt vmcnt(4)" ::: "memory");   // buf0 landed
    __builtin_amdgcn_s_barrier();
    asm volatile("" ::: "memory");

    bf16x8 a[4], bfr[4][2];
    #pragma unroll
    for (int k = 0; k < 4; ++k)
        #pragma unroll
        for (int nf = 0; nf < 2; ++nf) bfr[k][nf] = rB(0, k, nf);
    #pragma unroll
    for (int m = 0; m < 4; ++m) a[m] = rA(0, 0, m);

    for (int t = 0; t < 32; ++t) {
        const int t1 = 2 * t + 1;
        const int t2 = (2 * t + 2 < 64) ? 2 * t + 2 : 63;   // clamp (last iter)
        const int t3 = (2 * t + 3 < 64) ? 2 * t + 3 : 63;
        #pragma unroll
        for (int p = 0; p < 8; ++p) {
            const int cb = p >> 2;     // compute buffer
            const int q  = p & 3;      // kstep

            switch (p) {
                case 0: stage_half(1, 0, 0, t1, GA); break;
                case 1: stage_half(1, 0, 1, t1, GA); break;
                case 2: stage_half(0, 1, 0, t2, GB); break;
                case 3: stage_half(0, 1, 1, t2, GB); break;
                case 4: stage_half(0, 0, 0, t2, GA); break;
                case 5: stage_half(0, 0, 1, t2, GA); break;
                case 6: stage_half(1, 1, 0, t3, GB); break;
                case 7: stage_half(1, 1, 1, t3, GB); break;
            }

            __builtin_amdgcn_s_setprio(1);
            #pragma unroll
            for (int m = 0; m < 4; ++m)
                #pragma unroll
                for (int nf = 0; nf < 2; ++nf)
                    acc[m][nf] = __builtin_amdgcn_mfma_f32_32x32x16_bf16(
                        a[m], bfr[q][nf], acc[m][nf], 0, 0, 0);
            __builtin_amdgcn_s_setprio(0);

            // tail reads: preload next phase's fragments
            if (q == 0) {
                #pragma unroll
                for (int nf = 0; nf < 2; ++nf) bfr[2][nf] = rB(cb, 2, nf);
                #pragma unroll
                for (int nf = 0; nf < 2; ++nf) bfr[3][nf] = rB(cb, 3, nf);
                #pragma unroll
                for (int m = 0; m < 4; ++m)    a[m] = rA(cb, 1, m);
            } else if (q == 1) {
                #pragma unroll
                for (int m = 0; m < 4; ++m)    a[m] = rA(cb, 2, m);
            } else if (q == 2) {
                #pragma unroll
                for (int m = 0; m < 4; ++m)    a[m] = rA(cb, 3, m);
            } else {
                const int nb = cb ^ 1;   // other buffer (published at q2-end)
                #pragma unroll
                for (int nf = 0; nf < 2; ++nf) bfr[0][nf] = rB(nb, 0, nf);
                #pragma unroll
                for (int nf = 0; nf < 2; ++nf) bfr[1][nf] = rB(nb, 1, nf);
                #pragma unroll
                for (int m = 0; m < 4; ++m)    a[m] = rA(nb, 0, m);
            }

            if (q == 1)   // drain q0-tail reads before next B-stage
                asm volatile("s_waitcnt lgkmcnt(4)" ::: "memory");
            if (q == 2)   // publish other buffer (all but newest 2 drained)
                asm volatile("s_waitcnt vmcnt(2)" ::: "memory");
            if (q != 0) {
                __builtin_amdgcn_s_barrier();
                asm volatile("" ::: "memory");
            }
        }
    }

    // drain in-flight LDS stages before workgroup exit
    asm volatile("s_waitcnt vmcnt(0)" ::: "memory");

    // epilogue: C/D 32x32 layout col=lane&31, row=(r&3)+8*(r>>2)+4*(lane>>5)
    #pragma unroll
    for (int nf = 0; nf < 2; ++nf) {
        int col = bn + wn * 64 + nf * 32 + l31;
        float bv = bias[col];
        #pragma unroll
        for (int mf = 0; mf < 4; ++mf) {
            int rbase = bm + wm * 128 + mf * 32 + 4 * (lane >> 5);
            #pragma unroll
            for (int r = 0; r < 16; ++r) {
                int row = rbase + (r & 3) + 8 * (r >> 2);
                C[(size_t)row * N_T + col] = acc[mf][nf][r] + bv;
            }
        }
    }
}

// ---------------- fallback (fp32, no workspace needed) ----------------
__global__ void fallback_gemm(const float* __restrict__ X,
                              const int* __restrict__ q,
                              const float* __restrict__ sc,
                              const float* __restrict__ zr,
                              const float* __restrict__ bias,
                              float* __restrict__ C) {
    __shared__ float sX[16][17];
    __shared__ float sW[16][17];
    int tx = threadIdx.x, ty = threadIdx.y;
    int row = blockIdx.y * 16 + ty;
    int col = blockIdx.x * 16 + tx;
    float acc = 0.f;
    for (int k0 = 0; k0 < K_T; k0 += 16) {
        sX[ty][tx] = X[(size_t)row * K_T + k0 + tx];
        int wrow = blockIdx.x * 16 + ty;
        int kc = k0 + tx;
        int g = kc >> 7;
        sW[ty][tx] = ((float)q[(size_t)wrow * K_T + kc] - zr[wrow * NG + g]) * sc[wrow * NG + g];
        __syncthreads();
        #pragma unroll
        for (int kk = 0; kk < 16; ++kk) acc += sX[ty][kk] * sW[tx][kk];
        __syncthreads();
    }
    C[(size_t)row * N_T + col] = acc + bias[col];
}

// ---------------- launch ----------------
extern "C" void kernel_launch(void* const* d_in, const int* in_sizes, int n_in,
                              void* d_out, int out_size, void* d_ws, size_t ws_size,
                              hipStream_t stream) {
    const float* input   = (const float*)d_in[0];
    const int*   qweight = (const int*)d_in[1];
    const float* scales  = (const float*)d_in[2];
    const float* zeros   = (const float*)d_in[3];
    const float* bias    = (const float*)d_in[4];
    float* out = (float*)d_out;

    const size_t needW = (size_t)N_T * K_T * sizeof(unsigned short);   // 32 MB
    const size_t needX = (size_t)M_T * K_T * sizeof(unsigned short);   // 64 MB

    if (ws_size >= needW + needX) {
        unsigned short* Wb = (unsigned short*)d_ws;
        unsigned short* Xb = (unsigned short*)((char*)d_ws + needW);

        prep_kernel<<<49152, 256, 0, stream>>>(qweight, scales, zeros, input, Wb, Xb);
        gemm256_32x32<<<512, 512, 0, stream>>>(Xb, Wb, bias, out);
    } else {
        dim3 blk(16, 16);
        dim3 grid(N_T / 16, M_T / 16);
        fallback_gemm<<<grid, blk, 0, stream>>>(input, qweight, scales, zeros, bias, out);
    }
}

// Round 10
// 264.620 us; speedup vs baseline: 1.0909x; 1.0909x over previous
//
#include <hip/hip_runtime.h>
#include <hip/hip_bf16.h>
#include <cstdint>

typedef __attribute__((ext_vector_type(4))) float  floatx4;
typedef __attribute__((ext_vector_type(8))) __bf16 bf16x8;

#define M_T 8192   // tokens
#define N_T 4096   // out features
#define K_T 4096   // in features
#define NG  32

// fp32 -> bf16 round-to-nearest-even
__device__ __forceinline__ unsigned short f2bf(float f) {
    union { float f; unsigned int u; } v; v.f = f;
    unsigned int u = v.u;
    u += 0x7fffu + ((u >> 16) & 1u);
    return (unsigned short)(u >> 16);
}

// async global->LDS, 16B per lane; LDS dest wave-uniform base + lane*16.
__device__ __forceinline__ void load_lds16(const void* gsrc, void* ldst) {
    __builtin_amdgcn_global_load_lds(
        (const __attribute__((address_space(1))) uint32_t*)gsrc,
        (__attribute__((address_space(3))) uint32_t*)ldst,
        16, 0, 0);
}

// ---------------- merged prep kernel (verified) ----------------
__global__ void prep_kernel(const int* __restrict__ q,
                            const float* __restrict__ sc,
                            const float* __restrict__ zr,
                            const float* __restrict__ X,
                            unsigned short* __restrict__ Wb,
                            unsigned short* __restrict__ Xb) {
    int b = blockIdx.x;
    if (b < 16384) {
        int idx = b * 256 + threadIdx.x;
        int e0 = idx << 2;
        int row = e0 >> 12;
        int col = e0 & 4095;
        int g = col >> 7;
        float s = sc[(row << 5) + g];
        float z = zr[(row << 5) + g];
        int4 qv = *(const int4*)(q + e0);
        ushort4 o;
        o.x = f2bf(((float)qv.x - z) * s);
        o.y = f2bf(((float)qv.y - z) * s);
        o.z = f2bf(((float)qv.z - z) * s);
        o.w = f2bf(((float)qv.w - z) * s);
        *(ushort4*)(Wb + e0) = o;
    } else {
        int idx = (b - 16384) * 256 + threadIdx.x;
        int e0 = idx << 2;
        float4 xv = *(const float4*)(X + e0);
        ushort4 o;
        o.x = f2bf(xv.x); o.y = f2bf(xv.y); o.z = f2bf(xv.z); o.w = f2bf(xv.w);
        *(ushort4*)(Xb + e0) = o;
    }
}

// ---------------- 256x256 8-phase GEMM (R8 core, verified) + LDS epilogue ----
// C[M][N] = Xb[M][K] * Wb[N][K]^T + bias.
// 8 waves (2M x 4N), BK=64, LDS 128 KiB = 2 bufs x (A 2 halves + B 2 halves).
// K-loop identical to R8 (6 barriers / 8 phases, counted vmcnt/lgkm, hazard
// ledger in R8 header comment). New epilogue: stage acc+bias into LDS in two
// 128 KiB halves (slot-XOR block swizzle, write aliasing <=2-way), read back
// b128 row-contiguous, store 1 KiB contiguous dwordx4 per wave-row.
__global__ __launch_bounds__(512, 2) void gemm256_8ph(
    const unsigned short* __restrict__ Xb,
    const unsigned short* __restrict__ Wb,
    const float* __restrict__ bias,
    float* __restrict__ C)
{
    __shared__ __align__(16) unsigned short lds[65536];   // 128 KiB
    char* ldsb = (char*)lds;

    const int tid  = threadIdx.x;
    const int lane = tid & 63;
    const int wid  = tid >> 6;
    const int wm   = wid >> 2;    // 0..1
    const int wn   = wid & 3;     // 0..3

    // 2D XCD-aware swizzle. grid=512 = 8 XCD regions of 8Mx8N tiles.
    int bid = blockIdx.x;
    int xcd = bid & 7, r0 = bid >> 3;
    int mt = (xcd >> 1) * 8 + (r0 & 7);
    int nt = (xcd & 1) * 8 + (r0 >> 3);
    const int bm = mt * 256;
    const int bn = nt * 256;

    floatx4 acc[8][4] = {};

    const int klb  = (lane >> 4) * 16;
    const int axor = (lane & 7) << 4;

    int obA[2][2], obB[2][2];
    #pragma unroll
    for (int b = 0; b < 2; ++b)
        #pragma unroll
        for (int kp = 0; kp < 2; ++kp) {
            obA[b][kp] = b * 65536 + wm * 16384 + (lane & 15) * 128
                       + ((kp * 64 + klb) ^ axor);
            obB[b][kp] = b * 65536 + 32768 + (wn >> 1) * 16384 + (wn & 1) * 8192
                       + (lane & 15) * 128 + ((kp * 64 + klb) ^ axor);
        }

    auto rA = [&](int b, int kp, int mf) -> bf16x8 {
        return *(const bf16x8*)(ldsb + obA[b][kp] + mf * 2048);
    };
    auto rB = [&](int b, int kp, int nf) -> bf16x8 {
        return *(const bf16x8*)(ldsb + obB[b][kp] + nf * 2048);
    };

    const int pl0 = (wid * 8 + (lane >> 3)) * 8192
                  + (((lane & 7) * 16) ^ ((lane >> 3) << 4));
    const int pl1 = pl0 + 64 * 8192;
    const char* GA = (const char*)Xb + (size_t)bm * 8192;
    const char* GB = (const char*)Wb + (size_t)bn * 8192;

    auto stage_half = [&](int buf, int isB, int half, int tk, const char* G) {
        char* dst = ldsb + buf * 65536 + isB * 32768 + half * 16384 + wid * 1024;
        const char* s0 = G + ((size_t)half * 1048576 + (size_t)tk * 128);
        load_lds16(s0 + pl0, dst);
        load_lds16(s0 + pl1, dst + 8192);
    };

    // ---- prologue: buf0 <- tile0 (B,B,A,A), buf1.B <- tile1 ----
    stage_half(0, 1, 0, 0, GB);
    stage_half(0, 1, 1, 0, GB);
    stage_half(0, 0, 0, 0, GA);
    stage_half(0, 0, 1, 0, GA);
    stage_half(1, 1, 0, 1, GB);
    stage_half(1, 1, 1, 1, GB);
    asm volatile("s_waitcnt vmcnt(4)" ::: "memory");   // buf0 landed
    __builtin_amdgcn_s_barrier();
    asm volatile("" ::: "memory");

    bf16x8 a[4], bfr[4][2];
    #pragma unroll
    for (int nf = 0; nf < 4; ++nf) bfr[nf][0] = rB(0, 0, nf);
    #pragma unroll
    for (int m = 0; m < 4; ++m)    a[m] = rA(0, 0, m);

    for (int t = 0; t < 32; ++t) {
        const int t1 = 2 * t + 1;
        const int t2 = (2 * t + 2 < 64) ? 2 * t + 2 : 63;   // clamp (last iter)
        const int t3 = (2 * t + 3 < 64) ? 2 * t + 3 : 63;
        #pragma unroll
        for (int p = 0; p < 8; ++p) {
            const int cb    = p >> 2;
            const int q     = p & 3;
            const int kkp   = q >> 1;
            const int mbase = (q & 1) * 4;

            switch (p) {
                case 0: stage_half(1, 0, 0, t1, GA); break;
                case 1: stage_half(1, 0, 1, t1, GA); break;
                case 2: stage_half(0, 1, 0, t2, GB); break;
                case 3: stage_half(0, 1, 1, t2, GB); break;
                case 4: stage_half(0, 0, 0, t2, GA); break;
                case 5: stage_half(0, 0, 1, t2, GA); break;
                case 6: stage_half(1, 1, 0, t3, GB); break;
                case 7: stage_half(1, 1, 1, t3, GB); break;
            }

            __builtin_amdgcn_s_setprio(1);
            #pragma unroll
            for (int m = 0; m < 4; ++m)
                #pragma unroll
                for (int nf = 0; nf < 4; ++nf)
                    acc[mbase + m][nf] = __builtin_amdgcn_mfma_f32_16x16x32_bf16(
                        a[m], bfr[nf][kkp], acc[mbase + m][nf], 0, 0, 0);
            __builtin_amdgcn_s_setprio(0);

            // tail reads: preload NEXT phase's fragments
            if (q == 0) {
                #pragma unroll
                for (int nf = 0; nf < 4; ++nf) bfr[nf][1] = rB(cb, 1, nf);
                #pragma unroll
                for (int m = 0; m < 4; ++m)    a[m] = rA(cb, 0, 4 + m);
            } else if (q == 1) {
                #pragma unroll
                for (int m = 0; m < 4; ++m)    a[m] = rA(cb, 1, m);
            } else if (q == 2) {
                #pragma unroll
                for (int m = 0; m < 4; ++m)    a[m] = rA(cb, 1, 4 + m);
            } else {
                const int nb = cb ^ 1;   // other buffer (published at q2-end)
                #pragma unroll
                for (int nf = 0; nf < 4; ++nf) bfr[nf][0] = rB(nb, 0, nf);
                #pragma unroll
                for (int m = 0; m < 4; ++m)    a[m] = rA(nb, 0, m);
            }

            if (q == 1)   // drain q0-tail B-kk1 reads before next B-stage
                asm volatile("s_waitcnt lgkmcnt(4)" ::: "memory");
            if (q == 2)   // publish other buffer (all but newest 2 drained)
                asm volatile("s_waitcnt vmcnt(2)" ::: "memory");
            if (q != 0) { // ph0/ph4-end barriers removed (R8 proof)
                __builtin_amdgcn_s_barrier();
                asm volatile("" ::: "memory");
            }
        }
    }

    // ---- epilogue: drain everything, then LDS-transposed coalesced store ----
    asm volatile("s_waitcnt vmcnt(0) lgkmcnt(0)" ::: "memory");
    __builtin_amdgcn_s_barrier();
    asm volatile("" ::: "memory");

    const int l15 = lane & 15;
    float bv[4];
    #pragma unroll
    for (int nf = 0; nf < 4; ++nf)
        bv[nf] = bias[bn + wn * 64 + nf * 16 + l15];

    float* ldsf = (float*)ldsb;
    #pragma unroll
    for (int h = 0; h < 2; ++h) {
        // stage half h: rows (wm*128 + h*64 + [0,64)) -> slots wm*64+[0,64)
        // word col c stored at block (c>>2)^ (slot&7), word-in-block c&3.
        #pragma unroll
        for (int mf = 0; mf < 4; ++mf) {
            #pragma unroll
            for (int j = 0; j < 4; ++j) {
                int slot = wm * 64 + mf * 16 + (lane >> 4) * 4 + j;
                int sx = slot & 7;
                #pragma unroll
                for (int nf = 0; nf < 4; ++nf) {
                    int blk = (wn * 16 + nf * 4 + (l15 >> 2)) ^ sx;
                    ldsf[slot * 256 + blk * 4 + (lane & 3)] =
                        acc[h * 4 + mf][nf][j] + bv[nf];
                }
            }
        }
        __builtin_amdgcn_s_barrier();
        asm volatile("" ::: "memory");
        // readout: 16 slots/wave, each a 1 KiB contiguous row store
        #pragma unroll
        for (int i = 0; i < 16; ++i) {
            int slot = wid * 16 + i;
            int row  = bm + (slot >> 6) * 128 + h * 64 + (slot & 63);
            float4 v = *(const float4*)&ldsf[slot * 256 + ((lane ^ (slot & 7)) * 4)];
            *(float4*)&C[(size_t)row * N_T + bn + lane * 4] = v;
        }
        __builtin_amdgcn_s_barrier();
        asm volatile("" ::: "memory");
    }
}

// ---------------- fallback (fp32, no workspace needed) ----------------
__global__ void fallback_gemm(const float* __restrict__ X,
                              const int* __restrict__ q,
                              const float* __restrict__ sc,
                              const float* __restrict__ zr,
                              const float* __restrict__ bias,
                              float* __restrict__ C) {
    __shared__ float sX[16][17];
    __shared__ float sW[16][17];
    int tx = threadIdx.x, ty = threadIdx.y;
    int row = blockIdx.y * 16 + ty;
    int col = blockIdx.x * 16 + tx;
    float acc = 0.f;
    for (int k0 = 0; k0 < K_T; k0 += 16) {
        sX[ty][tx] = X[(size_t)row * K_T + k0 + tx];
        int wrow = blockIdx.x * 16 + ty;
        int kc = k0 + tx;
        int g = kc >> 7;
        sW[ty][tx] = ((float)q[(size_t)wrow * K_T + kc] - zr[wrow * NG + g]) * sc[wrow * NG + g];
        __syncthreads();
        #pragma unroll
        for (int kk = 0; kk < 16; ++kk) acc += sX[ty][kk] * sW[tx][kk];
        __syncthreads();
    }
    C[(size_t)row * N_T + col] = acc + bias[col];
}

// ---------------- launch ----------------
extern "C" void kernel_launch(void* const* d_in, const int* in_sizes, int n_in,
                              void* d_out, int out_size, void* d_ws, size_t ws_size,
                              hipStream_t stream) {
    const float* input   = (const float*)d_in[0];
    const int*   qweight = (const int*)d_in[1];
    const float* scales  = (const float*)d_in[2];
    const float* zeros   = (const float*)d_in[3];
    const float* bias    = (const float*)d_in[4];
    float* out = (float*)d_out;

    const size_t needW = (size_t)N_T * K_T * sizeof(unsigned short);   // 32 MB
    const size_t needX = (size_t)M_T * K_T * sizeof(unsigned short);   // 64 MB

    if (ws_size >= needW + needX) {
        unsigned short* Wb = (unsigned short*)d_ws;
        unsigned short* Xb = (unsigned short*)((char*)d_ws + needW);

        prep_kernel<<<49152, 256, 0, stream>>>(qweight, scales, zeros, input, Wb, Xb);
        gemm256_8ph<<<512, 512, 0, stream>>>(Xb, Wb, bias, out);
    } else {
        dim3 blk(16, 16);
        dim3 grid(N_T / 16, M_T / 16);
        fallback_gemm<<<grid, blk, 0, stream>>>(input, qweight, scales, zeros, bias, out);
    }
}